// Round 6
// baseline (3458.166 us; speedup 1.0000x reference)
//
#include <hip/hip_runtime.h>
#include <hip/hip_bf16.h>
#include <math.h>
#include <stdint.h>

// Problem constants
#define NQ 8
#define DIMV 256
#define KCODES 1024
#define NTOK 65536              // 32*2048
#define NELEM (NTOK * DIMV)     // 16777216
#define TOKPB 128               // tokens per block in layer kernel

typedef _Float16 f16x8 __attribute__((ext_vector_type(8)));
typedef float    f32x16 __attribute__((ext_vector_type(16)));

// rotate-left-3 of a 5-bit slot index (bijective bank-spreading permutation)
__device__ __forceinline__ int rotl3(int s) { return ((s << 3) | (s >> 2)) & 31; }

// sortable-uint encoding of fp32: a<b (float) <=> key(a)<key(b) (uint32)
__device__ __forceinline__ uint32_t fkey(float f) {
    uint32_t u = __float_as_uint(f);
    return ((int)u < 0) ? ~u : (u ^ 0x80000000u);
}

// ---------------------------------------------------------------------------
// Pre-pass 1: transpose embeds [q][d][k] -> embedT [q][k][d] (fp32, for the
// quantize gather in the update phase).
// ---------------------------------------------------------------------------
__global__ __launch_bounds__(256)
void vq_transpose(const float* __restrict__ embeds, float* __restrict__ embedT) {
    const int idx = blockIdx.x * 256 + threadIdx.x;       // 0 .. 2097151
    const int q   = idx >> 18;
    const int rem = idx & 262143;
    const int k   = rem >> 8;
    const int d   = rem & 255;
    embedT[idx] = embeds[q * 262144 + d * 1024 + k];
}

// Pre-pass 2: e2[q][k] = sum_d embed[q][d][k]^2 (fp32)
__global__ __launch_bounds__(256)
void vq_e2(const float* __restrict__ embeds, float* __restrict__ e2) {
    const int idx = blockIdx.x * 256 + threadIdx.x;       // 0 .. 8191
    const int q = idx >> 10;
    const int k = idx & 1023;
    const float* e = embeds + q * 262144 + k;
    float s = 0.f;
    for (int d = 0; d < DIMV; ++d) {
        const float v = e[d * 1024];
        s += v * v;
    }
    e2[idx] = s;
}

// ---------------------------------------------------------------------------
// Pre-pass 3: split embed into fp16 hi/lo laid out as per-(layer,chunk,range)
// 4 KB images read straight into registers by the layer kernel:
//   embedB[q][chunk(16)][w(16)][part(2)][s(128)][j(8)]   (halfs)
// s = h*64 + cl ; d = chunk*16 + h*8 + j ; k = w*64 + cl
// Fragment read: lane(l32,h32), tile ct -> s = h32*64 + ct*32 + l32
// (lane-contiguous 16B slots -> one coalesced global_load_dwordx4).
// ---------------------------------------------------------------------------
__global__ __launch_bounds__(256)
void vq_embedB(const float* __restrict__ embeds, _Float16* __restrict__ embedB) {
    const int idx = blockIdx.x * 256 + threadIdx.x;       // 0 .. 4194303
    const int j    = idx & 7;
    const int s    = (idx >> 3) & 127;
    const int part = (idx >> 10) & 1;
    const int w    = (idx >> 11) & 15;
    const int c    = (idx >> 15) & 15;
    const int q    = idx >> 19;
    const int h  = s >> 6;
    const int cl = s & 63;
    const int d  = c * 16 + h * 8 + j;
    const int k  = w * 64 + cl;
    const float v = embeds[q * 262144 + d * 1024 + k];
    const _Float16 hi = (_Float16)v;
    embedB[idx] = (part == 0) ? hi : (_Float16)(v - (float)hi);
}

// ---------------------------------------------------------------------------
// Per-layer VQ kernel: 512 blocks x 1024 threads (16 waves), 128 tokens/block.
// Two sequential passes over the codebook: pass p covers codes [p*512,p*512+512)
// with 16 waves = 2 token-subtiles(64) x 8 code-ranges(64). acc registers are
// reused across passes, halving per-block B traffic vs 64-token blocks.
// B loads go straight to registers (coalesced dwordx4, depth-1 prefetch).
// ---------------------------------------------------------------------------
// LDS layout (bytes):
//  [0,     65536)  A_hi : 128 rows x 256 d fp16; 16B-block s of row t at
//                         slot rotl3(s)^(t&31)
//  [65536,131072)  A_lo : same layout
//  [131072,147456) bestP: u64[16 entries][128 rows]  (entry = p*8+wr,
//                         ascending-code order for exact tie semantics)
//  [147456,147968) indF : int[128]
//  [147968,148032) lossRed float[16]
#define LDS_BYTES 148032

__global__ __launch_bounds__(1024)
void vq_layer(const float* __restrict__ resIn, float* __restrict__ resOut,
              const float* __restrict__ x, const float* __restrict__ embedTq,
              const float* __restrict__ e2q, const _Float16* __restrict__ embedBq,
              float* __restrict__ lossSumQ, int* __restrict__ countsQ,
              float* __restrict__ outp /* non-null on last layer */) {
    extern __shared__ char smem[];
    _Float16* Ahi = (_Float16*)smem;
    _Float16* Alo = (_Float16*)(smem + 65536);
    unsigned long long* bestP = (unsigned long long*)(smem + 131072);
    int*   indF    = (int*)(smem + 147456);
    float* lossRed = (float*)(smem + 147968);

    const int tid  = threadIdx.x;
    const int wave = tid >> 6;         // 0..15
    const int lane = tid & 63;
    const int l32  = lane & 31;
    const int h32  = lane >> 5;
    const int tsub = wave >> 3;        // token subtile 0/1
    const int wr   = wave & 7;         // code range within pass
    const int tok0 = blockIdx.x * TOKPB;

    // ---- Phase 0: stage residual -> A hi/lo (swizzled) ----
#pragma unroll
    for (int k = 0; k < 4; ++k) {
        const int si = tid + k * 1024;         // 0..4095 (t,s) pairs
        const int t  = si >> 5;                // 0..127
        const int s  = si & 31;
        const float4 v0 = *(const float4*)(resIn + (tok0 + t) * 256 + s * 8);
        const float4 v1 = *(const float4*)(resIn + (tok0 + t) * 256 + s * 8 + 4);
        const float vv[8] = {v0.x, v0.y, v0.z, v0.w, v1.x, v1.y, v1.z, v1.w};
        f16x8 h8, l8;
#pragma unroll
        for (int e = 0; e < 8; ++e) {
            const _Float16 hi = (_Float16)vv[e];
            h8[e] = hi;
            l8[e] = (_Float16)(vv[e] - (float)hi);
        }
        const int ss = rotl3(s) ^ (t & 31);
        ((f16x8*)(Ahi + t * 256))[ss] = h8;
        ((f16x8*)(Alo + t * 256))[ss] = l8;
    }
    __syncthreads();

    // ---- Two passes over the codebook ----
#pragma unroll 1
    for (int p = 0; p < 2; ++p) {
        const int codeBase = p * 512 + wr * 64;
        const int entry    = p * 8 + wr;       // ascending-code entry order

        f32x16 acc[2][2];
#pragma unroll
        for (int rt = 0; rt < 2; ++rt)
#pragma unroll
            for (int ct = 0; ct < 2; ++ct)
#pragma unroll
                for (int r = 0; r < 16; ++r) acc[rt][ct][r] = 0.f;

        // this lane's base into the (chunk, range) 4 KB image
        const char* gBw = (const char*)embedBq + entry * 4096 + h32 * 1024 + l32 * 16;

        f16x8 bH[2][2], bL[2][2];
#pragma unroll
        for (int ct = 0; ct < 2; ++ct) {
            bH[0][ct] = *(const f16x8*)(gBw + ct * 512);
            bL[0][ct] = *(const f16x8*)(gBw + 2048 + ct * 512);
        }

#pragma unroll
        for (int c = 0; c < 16; ++c) {
            const int cur = c & 1, nxt = cur ^ 1;
            if (c < 15) {
                const char* gBn = gBw + (c + 1) * 65536;
#pragma unroll
                for (int ct = 0; ct < 2; ++ct) {
                    bH[nxt][ct] = *(const f16x8*)(gBn + ct * 512);
                    bL[nxt][ct] = *(const f16x8*)(gBn + 2048 + ct * 512);
                }
            }
            f16x8 aH[2], aL[2];
#pragma unroll
            for (int rt = 0; rt < 2; ++rt) {
                const int t  = tsub * 64 + rt * 32 + l32;
                const int ss = rotl3(2 * c + h32) ^ l32;   // (t&31)==l32
                aH[rt] = ((const f16x8*)(Ahi + t * 256))[ss];
                aL[rt] = ((const f16x8*)(Alo + t * 256))[ss];
            }
#pragma unroll
            for (int rt = 0; rt < 2; ++rt)
#pragma unroll
                for (int ct = 0; ct < 2; ++ct) {
                    acc[rt][ct] = __builtin_amdgcn_mfma_f32_32x32x16_f16(
                        aH[rt], bH[cur][ct], acc[rt][ct], 0, 0, 0);
                    acc[rt][ct] = __builtin_amdgcn_mfma_f32_32x32x16_f16(
                        aH[rt], bL[cur][ct], acc[rt][ct], 0, 0, 0);
                    acc[rt][ct] = __builtin_amdgcn_mfma_f32_32x32x16_f16(
                        aL[rt], bH[cur][ct], acc[rt][ct], 0, 0, 0);
                }
        }

        // ---- scores + per-wave argmin (u64-packed, exact lexicographic) ----
        float e2v[2];
#pragma unroll
        for (int ct = 0; ct < 2; ++ct)
            e2v[ct] = e2q[codeBase + ct * 32 + l32];

#pragma unroll
        for (int rt = 0; rt < 2; ++rt) {
#pragma unroll
            for (int r = 0; r < 16; ++r) {
                unsigned long long cand = 0xffffffffffffffffULL;
#pragma unroll
                for (int ct = 0; ct < 2; ++ct) {
                    const float sc = e2v[ct] - 2.0f * acc[rt][ct][r];
                    const unsigned long long pk =
                        ((unsigned long long)fkey(sc) << 32) |
                        (uint32_t)(codeBase + ct * 32 + l32);
                    if (pk < cand) cand = pk;
                }
#pragma unroll
                for (int m = 1; m < 32; m <<= 1) {
                    const unsigned long long o = __shfl_xor(cand, m);
                    if (o < cand) cand = o;
                }
                if (l32 == 0) {
                    const int row = tsub * 64 + rt * 32 + (r & 3) + 8 * (r >> 2) + 4 * h32;
                    bestP[entry * 128 + row] = cand;
                }
            }
        }
    }
    __syncthreads();

    // ---- cross-entry argmin (entries in ascending code order) ----
    if (tid < 128) {
        unsigned long long b = bestP[tid];
        for (int e = 1; e < 16; ++e) {
            const unsigned long long o = bestP[e * 128 + tid];
            if (o < b) b = o;
        }
        const int bi = (int)(b & 0xffffffffu);
        indF[tid] = bi;
        atomicAdd(&countsQ[bi], 1);
    }
    __syncthreads();

    // ---- update: r -= quantize (into LDS); loss partial ----
    {
        const int tl = tid >> 3;          // token 0..127
        const int sg = tid & 7;           // 32-dim strip
        const int csel = indF[tl];
        const float* gq = embedTq + csel * 256 + sg * 32;
        float lp = 0.f;
        f16x8* rowH = (f16x8*)(Ahi + tl * 256);
        f16x8* rowL = (f16x8*)(Alo + tl * 256);
#pragma unroll
        for (int it = 0; it < 4; ++it) {
            const int slot = rotl3(sg * 4 + it) ^ (tl & 31);
            f16x8 h8 = rowH[slot];
            f16x8 l8 = rowL[slot];
            const float4 q0 = *(const float4*)(gq + it * 8);
            const float4 q1 = *(const float4*)(gq + it * 8 + 4);
            const float qv[8] = {q0.x, q0.y, q0.z, q0.w, q1.x, q1.y, q1.z, q1.w};
#pragma unroll
            for (int e = 0; e < 8; ++e) {
                const float rv = (float)h8[e] + (float)l8[e];
                const float nr = rv - qv[e];
                lp += nr * nr;
                const _Float16 nh = (_Float16)nr;
                h8[e] = nh;
                l8[e] = (_Float16)(nr - (float)nh);
            }
            rowH[slot] = h8;
            rowL[slot] = l8;
        }
        // loss reduction: wave -> block -> global atomic
#pragma unroll
        for (int off = 32; off > 0; off >>= 1) lp += __shfl_down(lp, off);
        if (lane == 0) lossRed[wave] = lp;
    }
    __syncthreads();
    if (tid == 0) {
        float t = 0.f;
        for (int w = 0; w < 16; ++w) t += lossRed[w];
        atomicAdd(lossSumQ, t);
    }
    __syncthreads();

    // ---- writeback ----
    if (outp == nullptr) {
        // new fp32 residual, coalesced
#pragma unroll
        for (int k = 0; k < 4; ++k) {
            const int si = tid + k * 1024;
            const int t  = si >> 5;
            const int s  = si & 31;
            const int ss = rotl3(s) ^ (t & 31);
            const f16x8 h8 = ((const f16x8*)(Ahi + t * 256))[ss];
            const f16x8 l8 = ((const f16x8*)(Alo + t * 256))[ss];
            float4 o0, o1;
            o0.x = (float)h8[0] + (float)l8[0];
            o0.y = (float)h8[1] + (float)l8[1];
            o0.z = (float)h8[2] + (float)l8[2];
            o0.w = (float)h8[3] + (float)l8[3];
            o1.x = (float)h8[4] + (float)l8[4];
            o1.y = (float)h8[5] + (float)l8[5];
            o1.z = (float)h8[6] + (float)l8[6];
            o1.w = (float)h8[7] + (float)l8[7];
            *(float4*)(resOut + (tok0 + t) * 256 + s * 8)     = o0;
            *(float4*)(resOut + (tok0 + t) * 256 + s * 8 + 4) = o1;
        }
    } else {
        // last layer: quantized_out = x - residual; residual not written
#pragma unroll
        for (int k = 0; k < 4; ++k) {
            const int si = tid + k * 1024;
            const int t  = si >> 5;
            const int s  = si & 31;
            const int ss = rotl3(s) ^ (t & 31);
            const f16x8 h8 = ((const f16x8*)(Ahi + t * 256))[ss];
            const f16x8 l8 = ((const f16x8*)(Alo + t * 256))[ss];
            const float* gx = x + (tok0 + t) * 256 + s * 8;
            const float4 x0 = *(const float4*)gx;
            const float4 x1 = *(const float4*)(gx + 4);
            float4 o0, o1;
            o0.x = x0.x - ((float)h8[0] + (float)l8[0]);
            o0.y = x0.y - ((float)h8[1] + (float)l8[1]);
            o0.z = x0.z - ((float)h8[2] + (float)l8[2]);
            o0.w = x0.w - ((float)h8[3] + (float)l8[3]);
            o1.x = x1.x - ((float)h8[4] + (float)l8[4]);
            o1.y = x1.y - ((float)h8[5] + (float)l8[5]);
            o1.z = x1.z - ((float)h8[6] + (float)l8[6]);
            o1.w = x1.w - ((float)h8[7] + (float)l8[7]);
            *(float4*)(outp + (tok0 + t) * 256 + s * 8)     = o0;
            *(float4*)(outp + (tok0 + t) * 256 + s * 8 + 4) = o1;
        }
    }
}

// ---------------------------------------------------------------------------
// Finalize: losses + perplexities into the output tail.
// ---------------------------------------------------------------------------
__global__ __launch_bounds__(256)
void vq_finalize(const int* __restrict__ counts, const float* __restrict__ lossSum,
                 float* __restrict__ outTail) {
    const int q = blockIdx.x;
    const int tid = threadIdx.x;
    float s = 0.f;
    for (int k = tid; k < KCODES; k += 256) {
        const float p = (float)counts[q * KCODES + k] * (1.0f / 65536.0f);
        s += p * logf(p + 1e-10f);
    }
    for (int off = 32; off > 0; off >>= 1) s += __shfl_down(s, off);
    __shared__ float wpart[4];
    if ((tid & 63) == 0) wpart[tid >> 6] = s;
    __syncthreads();
    if (tid == 0) {
        outTail[q]     = lossSum[q] * (1.0f / 16777216.0f);   // mean * COMMITMENT
        outTail[8 + q] = expf(-(wpart[0] + wpart[1] + wpart[2] + wpart[3]));
    }
}

// ---------------------------------------------------------------------------
extern "C" void kernel_launch(void* const* d_in, const int* in_sizes, int n_in,
                              void* d_out, int out_size, void* d_ws, size_t ws_size,
                              hipStream_t stream) {
    const float* x      = (const float*)d_in[0];   // [32,2048,256]
    const float* embeds = (const float*)d_in[1];   // [8,256,1024]
    float* out = (float*)d_out;                    // 16777216 + 8 + 8

    // Workspace layout (float units unless noted):
    float* residual = (float*)d_ws;                     // 16,777,216
    float* embedT   = residual + NELEM;                 // 2,097,152
    float* e2       = embedT + 2097152;                 // 8,192
    float* lossSum  = e2 + 8192;                        // 8
    int*   counts   = (int*)(lossSum + 8);              // 8,192
    _Float16* embedB = (_Float16*)(counts + 8192);      // 4,194,304 halfs (8 MB)

    hipMemsetAsync(lossSum, 0, (8 + 8192) * sizeof(float), stream);

    vq_transpose<<<8192, 256, 0, stream>>>(embeds, embedT);
    vq_e2<<<32, 256, 0, stream>>>(embeds, e2);
    vq_embedB<<<16384, 256, 0, stream>>>(embeds, embedB);

    hipFuncSetAttribute((const void*)vq_layer,
                        hipFuncAttributeMaxDynamicSharedMemorySize, LDS_BYTES);
    for (int q = 0; q < NQ; ++q) {
        const float* resIn = (q == 0) ? x : residual;
        vq_layer<<<NTOK / TOKPB, 1024, LDS_BYTES, stream>>>(
            resIn, residual, x,
            embedT + q * (KCODES * DIMV), e2 + q * KCODES,
            embedB + q * 524288, lossSum + q, counts + q * KCODES,
            (q == NQ - 1) ? out : nullptr);
    }

    vq_finalize<<<NQ, 256, 0, stream>>>(counts, lossSum, out + NELEM);
}